// Round 1
// baseline (2689.697 us; speedup 1.0000x reference)
//
#include <hip/hip_runtime.h>

#define NPTS   32768
#define NCODES 8192
#define DIM    256

#define DECAYF 0.99f
#define ONE_MINUS_DECAYF ((float)(1.0 - 0.99))
#define EPSF   1e-5f
#define KEPSF  ((float)(8192.0 * 1e-5))

// workspace byte offsets
#define WS_LOSS 0
#define WS_A    1024
#define WS_EN   (WS_A + NPTS * 4)
#define WS_CNT  (WS_EN + NCODES * 4)
#define WS_S    (WS_CNT + NCODES * 4)
#define WS_IDX  (WS_S + NCODES * 4)

// ---------------------------------------------------------------------------
// prep: out5 = 0.99 * ema_embedding ; zero counts + loss accumulator
__global__ __launch_bounds__(256) void k_prep(const float* __restrict__ ee,
                                              float* __restrict__ out5,
                                              int* __restrict__ cnt,
                                              double* __restrict__ loss) {
    int i = blockIdx.x * blockDim.x + threadIdx.x;
    int stride = gridDim.x * blockDim.x;
    for (int j = i; j < NCODES * DIM; j += stride)
        out5[j] = DECAYF * ee[j];
    if (i < NCODES) cnt[i] = 0;
    if (i == 0) *loss = 0.0;
}

// ---------------------------------------------------------------------------
// row squared-norm, one wave per row (DIM=256 = 64 lanes * float4).
// Accumulate in double, round once to fp32 (correctly-rounded sum of the
// fp32 squares -> best match for numpy's pairwise fp32 sum).
__global__ __launch_bounds__(256) void k_rownorm(const float* __restrict__ x,
                                                 float* __restrict__ outn,
                                                 int nrows) {
    int w = (blockIdx.x * blockDim.x + threadIdx.x) >> 6;
    int lane = threadIdx.x & 63;
    if (w >= nrows) return;
    const float4 v = *(const float4*)(x + (size_t)w * DIM + 4 * lane);
    float q0 = v.x * v.x, q1 = v.y * v.y, q2 = v.z * v.z, q3 = v.w * v.w;
    double s = (double)q0 + (double)q1 + (double)q2 + (double)q3;
    #pragma unroll
    for (int off = 32; off > 0; off >>= 1) s += __shfl_down(s, off);
    if (lane == 0) outn[w] = (float)s;
}

// ---------------------------------------------------------------------------
// distance argmin: BM=64 pts x BN=128 codes per block, TM=4 x TN=8 per thread,
// BD=32 k-chunks staged in LDS (register-transposed). dot accumulated
// strictly sequentially over d=0..255 with FMA (bit-matches BLAS sgemm).
__global__ __launch_bounds__(256) void k_argmin(const float* __restrict__ z,
                                                const float* __restrict__ emb,
                                                const float* __restrict__ A,
                                                const float* __restrict__ en,
                                                int* __restrict__ widx,
                                                float* __restrict__ out1) {
    constexpr int BM = 64, BN = 128, BD = 32;
    __shared__ float zs[BD][BM];    // 8 KB
    __shared__ float es[BD][BN];    // 16 KB
    __shared__ float pv[16][BM];    // 4 KB
    __shared__ int   pix[16][BM];   // 4 KB

    const int t  = threadIdx.x;
    const int tx = t & 15;   // point group (4 pts)
    const int ty = t >> 4;   // code group (8 codes)
    const int pBase = blockIdx.x * BM;

    float Areg[4];
    #pragma unroll
    for (int i = 0; i < 4; ++i) Areg[i] = A[pBase + 4 * tx + i];

    float best[4];
    int   bidx[4];
    #pragma unroll
    for (int i = 0; i < 4; ++i) { best[i] = __FLT_MAX__; bidx[i] = 0; }

    for (int cBase = 0; cBase < NCODES; cBase += BN) {
        float acc[4][8];
        #pragma unroll
        for (int i = 0; i < 4; ++i)
            #pragma unroll
            for (int j = 0; j < 8; ++j) acc[i][j] = 0.0f;

        for (int dBase = 0; dBase < DIM; dBase += BD) {
            __syncthreads();
            // stage e tile: 128 codes x 32 dims, transposed in registers
            {
                int cq = t & 31, dq = t >> 5;
                const float* src = emb + (size_t)(cBase + 4 * cq) * DIM + dBase + 4 * dq;
                float4 g0 = *(const float4*)(src);
                float4 g1 = *(const float4*)(src + DIM);
                float4 g2 = *(const float4*)(src + 2 * DIM);
                float4 g3 = *(const float4*)(src + 3 * DIM);
                *(float4*)&es[4 * dq + 0][4 * cq] = make_float4(g0.x, g1.x, g2.x, g3.x);
                *(float4*)&es[4 * dq + 1][4 * cq] = make_float4(g0.y, g1.y, g2.y, g3.y);
                *(float4*)&es[4 * dq + 2][4 * cq] = make_float4(g0.z, g1.z, g2.z, g3.z);
                *(float4*)&es[4 * dq + 3][4 * cq] = make_float4(g0.w, g1.w, g2.w, g3.w);
            }
            // stage z tile: 64 pts x 32 dims
            if (t < 128) {
                int pq = t & 15, dq = t >> 4;
                const float* src = z + (size_t)(pBase + 4 * pq) * DIM + dBase + 4 * dq;
                float4 g0 = *(const float4*)(src);
                float4 g1 = *(const float4*)(src + DIM);
                float4 g2 = *(const float4*)(src + 2 * DIM);
                float4 g3 = *(const float4*)(src + 3 * DIM);
                *(float4*)&zs[4 * dq + 0][4 * pq] = make_float4(g0.x, g1.x, g2.x, g3.x);
                *(float4*)&zs[4 * dq + 1][4 * pq] = make_float4(g0.y, g1.y, g2.y, g3.y);
                *(float4*)&zs[4 * dq + 2][4 * pq] = make_float4(g0.z, g1.z, g2.z, g3.z);
                *(float4*)&zs[4 * dq + 3][4 * pq] = make_float4(g0.w, g1.w, g2.w, g3.w);
            }
            __syncthreads();

            #pragma unroll
            for (int d = 0; d < BD; ++d) {
                const float4 a  = *(const float4*)&zs[d][4 * tx];
                const float4 b0 = *(const float4*)&es[d][8 * ty];
                const float4 b1 = *(const float4*)&es[d][8 * ty + 4];
                const float av[4] = {a.x, a.y, a.z, a.w};
                const float bv[8] = {b0.x, b0.y, b0.z, b0.w, b1.x, b1.y, b1.z, b1.w};
                #pragma unroll
                for (int i = 0; i < 4; ++i)
                    #pragma unroll
                    for (int j = 0; j < 8; ++j)
                        acc[i][j] += av[i] * bv[j];
            }
        }

        // running argmin update; code order within thread is ascending ->
        // strict < keeps the first (lowest-index) minimum
        #pragma unroll
        for (int j = 0; j < 8; ++j) {
            int code = cBase + 8 * ty + j;
            float e2 = en[code];
            #pragma unroll
            for (int i = 0; i < 4; ++i) {
                // ref: (||z||^2 - 2*dot) + ||e||^2, fp32 step-by-step.
                // 2*dot is exact, so fma contraction of (A - 2*acc) is
                // bit-identical to the separate mul+sub.
                float dist = (Areg[i] - 2.0f * acc[i][j]) + e2;
                if (dist < best[i]) { best[i] = dist; bidx[i] = code; }
            }
        }
    }

    // cross-thread merge (code ranges interleave across ty -> need index
    // tie-break to match numpy's first-occurrence argmin)
    __syncthreads();
    #pragma unroll
    for (int i = 0; i < 4; ++i) {
        pv[ty][4 * tx + i]  = best[i];
        pix[ty][4 * tx + i] = bidx[i];
    }
    __syncthreads();
    if (t < 64) {
        float bv = pv[0][t];
        int   bi = pix[0][t];
        #pragma unroll
        for (int y = 1; y < 16; ++y) {
            float v = pv[y][t];
            int   ix = pix[y][t];
            if (v < bv || (v == bv && ix < bi)) { bv = v; bi = ix; }
        }
        widx[pBase + t] = bi;
        out1[pBase + t] = (float)bi;
    }
}

// ---------------------------------------------------------------------------
// scatter: one wave per point. Writes z_q_st, accumulates dw (scaled) into
// out5 via atomics, counts via int atomics, loss via double atomic.
__global__ __launch_bounds__(256) void k_scatter(const float* __restrict__ z,
                                                 const float* __restrict__ emb,
                                                 const int* __restrict__ widx,
                                                 float* __restrict__ out0,
                                                 float* __restrict__ out5,
                                                 int* __restrict__ cnt,
                                                 double* __restrict__ loss) {
    int w = (blockIdx.x * blockDim.x + threadIdx.x) >> 6;  // point id
    int lane = threadIdx.x & 63;
    int idx = widx[w];
    const float4 zv = *(const float4*)(z + (size_t)w * DIM + 4 * lane);
    const float4 ev = *(const float4*)(emb + (size_t)idx * DIM + 4 * lane);

    // z_q_st = z_q + (z - z_q), fp32 ops to bit-match reference
    float4 o;
    o.x = ev.x + (zv.x - ev.x);
    o.y = ev.y + (zv.y - ev.y);
    o.z = ev.z + (zv.z - ev.z);
    o.w = ev.w + (zv.w - ev.w);
    *(float4*)(out0 + (size_t)w * DIM + 4 * lane) = o;

    float* dst = out5 + (size_t)idx * DIM + 4 * lane;
    atomicAdd(dst + 0, ONE_MINUS_DECAYF * zv.x);
    atomicAdd(dst + 1, ONE_MINUS_DECAYF * zv.y);
    atomicAdd(dst + 2, ONE_MINUS_DECAYF * zv.z);
    atomicAdd(dst + 3, ONE_MINUS_DECAYF * zv.w);

    float t0 = ev.x - zv.x, t1 = ev.y - zv.y, t2 = ev.z - zv.z, t3 = ev.w - zv.w;
    float s0 = t0 * t0, s1 = t1 * t1, s2 = t2 * t2, s3 = t3 * t3;
    double ls = (double)s0 + (double)s1 + (double)s2 + (double)s3;
    #pragma unroll
    for (int off = 32; off > 0; off >>= 1) ls += __shfl_down(ls, off);
    if (lane == 0) {
        atomicAdd(loss, ls);
        atomicAdd(cnt + idx, 1);
    }
}

// ---------------------------------------------------------------------------
// single block: out4 = ema_cs*0.99 + cnt*(1-0.99); n = sum(out4);
// smoothed[k]; vq_loss
__global__ __launch_bounds__(256) void k_n(const float* __restrict__ ecs,
                                           const int* __restrict__ cnt,
                                           float* __restrict__ out4,
                                           float* __restrict__ s_out,
                                           const double* __restrict__ loss,
                                           float* __restrict__ out2) {
    __shared__ double red[256];
    __shared__ float nsh;
    int t = threadIdx.x;
    double local = 0.0;
    for (int k = t; k < NCODES; k += 256) {
        float ncs = ecs[k] * DECAYF + (float)cnt[k] * ONE_MINUS_DECAYF;
        out4[k] = ncs;
        local += (double)ncs;
    }
    red[t] = local;
    __syncthreads();
    for (int off = 128; off > 0; off >>= 1) {
        if (t < off) red[t] += red[t + off];
        __syncthreads();
    }
    if (t == 0) {
        nsh = (float)red[0];
        out2[0] = 0.25f * (float)(*loss / (double)((size_t)NPTS * DIM));
    }
    __syncthreads();
    float n = nsh;
    for (int k = t; k < NCODES; k += 256) {
        // ref: (ncs + eps) / (n + K*eps) * n   (left-to-right fp32)
        s_out[k] = (out4[k] + EPSF) / (n + KEPSF) * n;
    }
}

// ---------------------------------------------------------------------------
__global__ __launch_bounds__(256) void k_final(const float* __restrict__ out5,
                                               const float* __restrict__ s,
                                               float* __restrict__ out3) {
    int i = blockIdx.x * blockDim.x + threadIdx.x;
    int stride = gridDim.x * blockDim.x;
    for (int j = i; j < NCODES * DIM; j += stride)
        out3[j] = out5[j] / s[j >> 8];
}

// ---------------------------------------------------------------------------
extern "C" void kernel_launch(void* const* d_in, const int* in_sizes, int n_in,
                              void* d_out, int out_size, void* d_ws, size_t ws_size,
                              hipStream_t stream) {
    const float* z   = (const float*)d_in[0];           // [32768, 256]
    const float* emb = (const float*)d_in[1];           // [8192, 256]
    const float* ecs = (const float*)d_in[2];           // [8192]
    const float* eem = (const float*)d_in[3];           // [8192, 256]

    float* out = (float*)d_out;
    float* out0 = out;                   // z_q_st         [8388608]
    float* out1 = out + 8388608;         // indices        [32768]
    float* out2 = out + 8421376;         // vq_loss        [1]
    float* out3 = out + 8421377;         // new_embedding  [2097152]
    float* out4 = out + 10518529;        // new_ema_cs     [8192]
    float* out5 = out + 10526721;        // new_ema_emb    [2097152]

    char* ws = (char*)d_ws;
    double* wloss = (double*)(ws + WS_LOSS);
    float*  wA    = (float*)(ws + WS_A);
    float*  wEn   = (float*)(ws + WS_EN);
    int*    wCnt  = (int*)(ws + WS_CNT);
    float*  wS    = (float*)(ws + WS_S);
    int*    wIdx  = (int*)(ws + WS_IDX);

    hipLaunchKernelGGL(k_prep, dim3(2048), dim3(256), 0, stream, eem, out5, wCnt, wloss);
    hipLaunchKernelGGL(k_rownorm, dim3(NPTS / 4), dim3(256), 0, stream, z, wA, NPTS);
    hipLaunchKernelGGL(k_rownorm, dim3(NCODES / 4), dim3(256), 0, stream, emb, wEn, NCODES);
    hipLaunchKernelGGL(k_argmin, dim3(NPTS / 64), dim3(256), 0, stream,
                       z, emb, wA, wEn, wIdx, out1);
    hipLaunchKernelGGL(k_scatter, dim3(NPTS / 4), dim3(256), 0, stream,
                       z, emb, wIdx, out0, out5, wCnt, wloss);
    hipLaunchKernelGGL(k_n, dim3(1), dim3(256), 0, stream, ecs, wCnt, out4, wS, wloss, out2);
    hipLaunchKernelGGL(k_final, dim3(2048), dim3(256), 0, stream, out5, wS, out3);
}

// Round 2
// 1854.660 us; speedup vs baseline: 1.4502x; 1.4502x over previous
//
#include <hip/hip_runtime.h>

#define NPTS   32768
#define NCODES 8192
#define DIM    256

#define DECAYF 0.99f
#define ONE_MINUS_DECAYF ((float)(1.0 - 0.99))
#define EPSF   1e-5f
#define KEPSF  ((float)(8192.0 * 1e-5))
#define MARGIN 0.05f

// workspace byte offsets
#define WS_LOSS  0
#define WS_A     1024
#define WS_EN    (WS_A + NPTS * 4)
#define WS_CNT   (WS_EN + NCODES * 4)
#define WS_S     (WS_CNT + NCODES * 4)
#define WS_IDX   (WS_S + NCODES * 4)
#define WS_STRIP (WS_IDX + NPTS * 4)                 // 32768*64*8 = 16 MB
#define WS_AHL   (WS_STRIP + (size_t)NPTS * 64 * 8)  // 32768*768*2 = 48 MB
#define WS_BHL   (WS_AHL + (size_t)NPTS * 768 * 2)   // 8192*768*2  = 12 MB

typedef __attribute__((ext_vector_type(8))) short short8;
typedef __attribute__((ext_vector_type(4))) float f32x4;

__device__ inline void gl_lds16(const void* g, void* l) {
    __builtin_amdgcn_global_load_lds(
        (const __attribute__((address_space(1))) void*)g,
        (__attribute__((address_space(3))) void*)l, 16, 0, 0);
}

__device__ inline unsigned short f2bf(float f) {  // RNE float->bf16
    unsigned u = __float_as_uint(f);
    return (unsigned short)((u + 0x7FFFu + ((u >> 16) & 1u)) >> 16);
}
__device__ inline unsigned f2ord(float f) {       // monotone float->uint
    unsigned u = __float_as_uint(f);
    return (u & 0x80000000u) ? ~u : (u | 0x80000000u);
}
__device__ inline float ord2f(unsigned o) {
    unsigned u = (o & 0x80000000u) ? (o & 0x7FFFFFFFu) : ~o;
    return __uint_as_float(u);
}

// ---------------------------------------------------------------------------
__global__ __launch_bounds__(256) void k_prep(const float* __restrict__ ee,
                                              float* __restrict__ out5,
                                              int* __restrict__ cnt,
                                              double* __restrict__ loss) {
    int i = blockIdx.x * blockDim.x + threadIdx.x;
    int stride = gridDim.x * blockDim.x;
    for (int j = i; j < NCODES * DIM; j += stride)
        out5[j] = DECAYF * ee[j];
    if (i < NCODES) cnt[i] = 0;
    if (i == 0) *loss = 0.0;
}

// ---------------------------------------------------------------------------
__global__ __launch_bounds__(256) void k_rownorm(const float* __restrict__ x,
                                                 float* __restrict__ outn,
                                                 int nrows) {
    int w = (blockIdx.x * blockDim.x + threadIdx.x) >> 6;
    int lane = threadIdx.x & 63;
    if (w >= nrows) return;
    const float4 v = *(const float4*)(x + (size_t)w * DIM + 4 * lane);
    float q0 = v.x * v.x, q1 = v.y * v.y, q2 = v.z * v.z, q3 = v.w * v.w;
    double s = (double)q0 + (double)q1 + (double)q2 + (double)q3;
    #pragma unroll
    for (int off = 32; off > 0; off >>= 1) s += __shfl_down(s, off);
    if (lane == 0) outn[w] = (float)s;
}

// ---------------------------------------------------------------------------
// hi/lo bf16 split. mode 0 (z): cols [hi | lo | hi]; mode 1 (e): [hi | hi | lo]
__global__ __launch_bounds__(256) void k_split(const float* __restrict__ x,
                                               unsigned short* __restrict__ dst,
                                               int nelem, int mode) {
    int i = blockIdx.x * blockDim.x + threadIdx.x;
    int stride = gridDim.x * blockDim.x;
    for (int j = i; j < nelem; j += stride) {
        float v = x[j];
        unsigned short h = f2bf(v);
        float hf = __uint_as_float((unsigned)h << 16);
        unsigned short lo = f2bf(v - hf);
        int row = j >> 8, d = j & 255;
        size_t b = (size_t)row * 768 + d;
        if (mode == 0) { dst[b] = h;  dst[b + 256] = lo; dst[b + 512] = h; }
        else           { dst[b] = h;  dst[b + 256] = h;  dst[b + 512] = lo; }
    }
}

// ---------------------------------------------------------------------------
// Phase 1: bf16 MFMA GEMM (M=32768, N=8192, K=768) with fused per-strip argmin.
// BM=BN=128, BK=64; 4 waves in 2x2; 16B-granular XOR swizzle on LDS so both
// global_load_lds (linear) and frag ds_read_b128 (row-strided) are conflict-ok.
__global__ __launch_bounds__(256) void k_gemm_argmin(
    const unsigned short* __restrict__ Ahl,   // [NPTS][768] bf16 bits
    const unsigned short* __restrict__ Bhl,   // [NCODES][768] bf16 bits
    const float* __restrict__ en,
    unsigned long long* __restrict__ strip) { // [NPTS][64]
    __shared__ __align__(16) unsigned short AT[8192];  // 16 KB: 1024 chunks
    __shared__ __align__(16) unsigned short BT[8192];  // 16 KB
    __shared__ unsigned long long pmin[2][128];

    const int t = threadIdx.x;
    const int w = t >> 6, l = t & 63;
    const int quad = l >> 4, l15 = l & 15;
    const int wr = w >> 1, wc = w & 1;
    const int mb = blockIdx.x >> 6, nb = blockIdx.x & 63;
    const int mBase = mb * 128, nBase = nb * 128;

    // staging: thread t covers slots {i*256+t}; slot s: row=s>>3, x=s&7,
    // kchunk = x ^ (row&7). row = i*32 + (t>>3) -> row&7 == (t>>3)&7 for all i.
    const int xr = (t & 7) ^ ((t >> 3) & 7);
    const int rrow = t >> 3;
    const unsigned short* ag[4];
    const unsigned short* bg[4];
    #pragma unroll
    for (int i = 0; i < 4; ++i) {
        ag[i] = Ahl + (size_t)(mBase + i * 32 + rrow) * 768 + xr * 8;
        bg[i] = Bhl + (size_t)(nBase + i * 32 + rrow) * 768 + xr * 8;
    }

    f32x4 acc[4][4];
    #pragma unroll
    for (int i = 0; i < 4; ++i)
        #pragma unroll
        for (int j = 0; j < 4; ++j)
            acc[i][j] = (f32x4){0.f, 0.f, 0.f, 0.f};

    for (int kt = 0; kt < 12; ++kt) {
        __syncthreads();
        #pragma unroll
        for (int i = 0; i < 4; ++i) {
            // dst base is wave-uniform; HW adds lane*16
            gl_lds16(ag[i], &AT[(i * 256 + w * 64) * 8]);
            gl_lds16(bg[i], &BT[(i * 256 + w * 64) * 8]);
            ag[i] += 64; bg[i] += 64;
        }
        __syncthreads();
        #pragma unroll
        for (int kk = 0; kk < 2; ++kk) {
            const int kc = kk * 4 + quad;
            short8 a[4], b[4];
            #pragma unroll
            for (int ti = 0; ti < 4; ++ti) {
                int m = wr * 64 + ti * 16 + l15;
                a[ti] = *(const short8*)&AT[(m * 8 + (kc ^ (m & 7))) * 8];
                int n = wc * 64 + ti * 16 + l15;
                b[ti] = *(const short8*)&BT[(n * 8 + (kc ^ (n & 7))) * 8];
            }
            #pragma unroll
            for (int ti = 0; ti < 4; ++ti)
                #pragma unroll
                for (int tj = 0; tj < 4; ++tj)
                    acc[ti][tj] = __builtin_amdgcn_mfma_f32_16x16x32_bf16(
                        a[ti], b[tj], acc[ti][tj], 0, 0, 0);
        }
    }

    // epilogue: per-point argmin over this block's 128 codes
    float enc[4];
    #pragma unroll
    for (int tj = 0; tj < 4; ++tj)
        enc[tj] = en[nBase + wc * 64 + tj * 16 + l15];

    #pragma unroll
    for (int ti = 0; ti < 4; ++ti) {
        #pragma unroll
        for (int r = 0; r < 4; ++r) {
            unsigned long long best = ~0ull;
            #pragma unroll
            for (int tj = 0; tj < 4; ++tj) {
                float d = enc[tj] - 2.0f * acc[ti][tj][r];
                unsigned code = (unsigned)(nBase + wc * 64 + tj * 16 + l15);
                unsigned long long pk = ((unsigned long long)f2ord(d) << 32) | code;
                best = pk < best ? pk : best;
            }
            #pragma unroll
            for (int off = 1; off < 16; off <<= 1) {
                unsigned long long o = __shfl_xor(best, off);
                best = o < best ? o : best;
            }
            if (l15 == 0) pmin[wc][wr * 64 + ti * 16 + quad * 4 + r] = best;
        }
    }
    __syncthreads();
    if (t < 128) {
        unsigned long long a0 = pmin[0][t], b0 = pmin[1][t];
        strip[(size_t)(mBase + t) * 64 + nb] = a0 < b0 ? a0 : b0;
    }
}

// ---------------------------------------------------------------------------
// Phase 2: one wave per point. Reduce strip minima, rescore candidate strips
// with round-1 exact fp32 semantics (sequential FMA dot, same distance expr,
// lowest-index tie-break).
__global__ __launch_bounds__(256) void k_phase2(
    const float* __restrict__ z, const float* __restrict__ emb,
    const float* __restrict__ A, const float* __restrict__ en,
    const unsigned long long* __restrict__ strip,
    int* __restrict__ widx, float* __restrict__ out1) {
    int wpt = (blockIdx.x << 2) + (threadIdx.x >> 6);  // point id
    int l = threadIdx.x & 63;

    unsigned long long e0 = strip[(size_t)wpt * 64 + l];
    unsigned long long g = e0;
    #pragma unroll
    for (int off = 1; off < 64; off <<= 1) {
        unsigned long long o = __shfl_xor(g, off);
        g = o < g ? o : g;
    }
    float gd = ord2f((unsigned)(g >> 32));
    bool flag = ord2f((unsigned)(e0 >> 32)) <= gd + MARGIN;
    unsigned long long mask = __ballot(flag);

    const float* zr = z + (size_t)wpt * DIM;
    float Azn = A[wpt];
    unsigned long long best = ~0ull;
    while (mask) {
        int s = __ffsll((long long)mask) - 1;
        mask &= mask - 1;
        #pragma unroll
        for (int h = 0; h < 2; ++h) {
            int c = s * 128 + h * 64 + l;
            const float* er = emb + (size_t)c * DIM;
            float acc = 0.f;
            for (int d = 0; d < DIM; ++d) acc = fmaf(zr[d], er[d], acc);
            float dist = (Azn - 2.0f * acc) + en[c];
            unsigned long long pk =
                ((unsigned long long)f2ord(dist) << 32) | (unsigned)c;
            best = pk < best ? pk : best;
        }
    }
    #pragma unroll
    for (int off = 1; off < 64; off <<= 1) {
        unsigned long long o = __shfl_xor(best, off);
        best = o < best ? o : best;
    }
    if (l == 0) {
        int idx = (int)(unsigned)best;
        widx[wpt] = idx;
        out1[wpt] = (float)idx;
    }
}

// ---------------------------------------------------------------------------
__global__ __launch_bounds__(256) void k_scatter(const float* __restrict__ z,
                                                 const float* __restrict__ emb,
                                                 const int* __restrict__ widx,
                                                 float* __restrict__ out0,
                                                 float* __restrict__ out5,
                                                 int* __restrict__ cnt,
                                                 double* __restrict__ loss) {
    int w = (blockIdx.x * blockDim.x + threadIdx.x) >> 6;  // point id
    int lane = threadIdx.x & 63;
    int idx = widx[w];
    const float4 zv = *(const float4*)(z + (size_t)w * DIM + 4 * lane);
    const float4 ev = *(const float4*)(emb + (size_t)idx * DIM + 4 * lane);

    float4 o;
    o.x = ev.x + (zv.x - ev.x);
    o.y = ev.y + (zv.y - ev.y);
    o.z = ev.z + (zv.z - ev.z);
    o.w = ev.w + (zv.w - ev.w);
    *(float4*)(out0 + (size_t)w * DIM + 4 * lane) = o;

    float* dst = out5 + (size_t)idx * DIM + 4 * lane;
    atomicAdd(dst + 0, ONE_MINUS_DECAYF * zv.x);
    atomicAdd(dst + 1, ONE_MINUS_DECAYF * zv.y);
    atomicAdd(dst + 2, ONE_MINUS_DECAYF * zv.z);
    atomicAdd(dst + 3, ONE_MINUS_DECAYF * zv.w);

    float t0 = ev.x - zv.x, t1 = ev.y - zv.y, t2 = ev.z - zv.z, t3 = ev.w - zv.w;
    float s0 = t0 * t0, s1 = t1 * t1, s2 = t2 * t2, s3 = t3 * t3;
    double ls = (double)s0 + (double)s1 + (double)s2 + (double)s3;
    #pragma unroll
    for (int off = 32; off > 0; off >>= 1) ls += __shfl_down(ls, off);
    if (lane == 0) {
        atomicAdd(loss, ls);
        atomicAdd(cnt + idx, 1);
    }
}

// ---------------------------------------------------------------------------
__global__ __launch_bounds__(256) void k_n(const float* __restrict__ ecs,
                                           const int* __restrict__ cnt,
                                           float* __restrict__ out4,
                                           float* __restrict__ s_out,
                                           const double* __restrict__ loss,
                                           float* __restrict__ out2) {
    __shared__ double red[256];
    __shared__ float nsh;
    int t = threadIdx.x;
    double local = 0.0;
    for (int k = t; k < NCODES; k += 256) {
        float ncs = ecs[k] * DECAYF + (float)cnt[k] * ONE_MINUS_DECAYF;
        out4[k] = ncs;
        local += (double)ncs;
    }
    red[t] = local;
    __syncthreads();
    for (int off = 128; off > 0; off >>= 1) {
        if (t < off) red[t] += red[t + off];
        __syncthreads();
    }
    if (t == 0) {
        nsh = (float)red[0];
        out2[0] = 0.25f * (float)(*loss / (double)((size_t)NPTS * DIM));
    }
    __syncthreads();
    float n = nsh;
    for (int k = t; k < NCODES; k += 256)
        s_out[k] = (out4[k] + EPSF) / (n + KEPSF) * n;
}

// ---------------------------------------------------------------------------
__global__ __launch_bounds__(256) void k_final(const float* __restrict__ out5,
                                               const float* __restrict__ s,
                                               float* __restrict__ out3) {
    int i = blockIdx.x * blockDim.x + threadIdx.x;
    int stride = gridDim.x * blockDim.x;
    for (int j = i; j < NCODES * DIM; j += stride)
        out3[j] = out5[j] / s[j >> 8];
}

// ---------------------------------------------------------------------------
extern "C" void kernel_launch(void* const* d_in, const int* in_sizes, int n_in,
                              void* d_out, int out_size, void* d_ws, size_t ws_size,
                              hipStream_t stream) {
    const float* z   = (const float*)d_in[0];
    const float* emb = (const float*)d_in[1];
    const float* ecs = (const float*)d_in[2];
    const float* eem = (const float*)d_in[3];

    float* out = (float*)d_out;
    float* out0 = out;                   // z_q_st         [8388608]
    float* out1 = out + 8388608;         // indices        [32768]
    float* out2 = out + 8421376;         // vq_loss        [1]
    float* out3 = out + 8421377;         // new_embedding  [2097152]
    float* out4 = out + 10518529;        // new_ema_cs     [8192]
    float* out5 = out + 10526721;        // new_ema_emb    [2097152]

    char* ws = (char*)d_ws;
    double* wloss = (double*)(ws + WS_LOSS);
    float*  wA    = (float*)(ws + WS_A);
    float*  wEn   = (float*)(ws + WS_EN);
    int*    wCnt  = (int*)(ws + WS_CNT);
    float*  wS    = (float*)(ws + WS_S);
    int*    wIdx  = (int*)(ws + WS_IDX);
    unsigned long long* wStrip = (unsigned long long*)(ws + WS_STRIP);
    unsigned short* wAhl = (unsigned short*)(ws + WS_AHL);
    unsigned short* wBhl = (unsigned short*)(ws + WS_BHL);

    hipLaunchKernelGGL(k_prep, dim3(2048), dim3(256), 0, stream, eem, out5, wCnt, wloss);
    hipLaunchKernelGGL(k_rownorm, dim3(NPTS / 4), dim3(256), 0, stream, z, wA, NPTS);
    hipLaunchKernelGGL(k_rownorm, dim3(NCODES / 4), dim3(256), 0, stream, emb, wEn, NCODES);
    hipLaunchKernelGGL(k_split, dim3(4096), dim3(256), 0, stream, z, wAhl, NPTS * DIM, 0);
    hipLaunchKernelGGL(k_split, dim3(2048), dim3(256), 0, stream, emb, wBhl, NCODES * DIM, 1);
    hipLaunchKernelGGL(k_gemm_argmin, dim3((NPTS / 128) * (NCODES / 128)), dim3(256), 0, stream,
                       wAhl, wBhl, wEn, wStrip);
    hipLaunchKernelGGL(k_phase2, dim3(NPTS / 4), dim3(256), 0, stream,
                       z, emb, wA, wEn, wStrip, wIdx, out1);
    hipLaunchKernelGGL(k_scatter, dim3(NPTS / 4), dim3(256), 0, stream,
                       z, emb, wIdx, out0, out5, wCnt, wloss);
    hipLaunchKernelGGL(k_n, dim3(1), dim3(256), 0, stream, ecs, wCnt, out4, wS, wloss, out2);
    hipLaunchKernelGGL(k_final, dim3(2048), dim3(256), 0, stream, out5, wS, out3);
}

// Round 3
// 1193.876 us; speedup vs baseline: 2.2529x; 1.5535x over previous
//
#include <hip/hip_runtime.h>

#define NPTS   32768
#define NCODES 8192
#define DIM    256

#define DECAYF 0.99f
#define ONE_MINUS_DECAYF ((float)(1.0 - 0.99))
#define EPSF   1e-5f
#define KEPSF  ((float)(8192.0 * 1e-5))
#define MARGIN 0.02f

// workspace byte offsets
#define WS_LOSS  0
#define WS_A     1024                                  // 128 KB
#define WS_EN    (WS_A + NPTS * 4)                     // 32 KB
#define WS_CNT   (WS_EN + NCODES * 4)                  // 32 KB
#define WS_S     (WS_CNT + NCODES * 4)                 // 32 KB
#define WS_IDX   (WS_S + NCODES * 4)                   // 128 KB
#define WS_EMBT  (WS_IDX + NPTS * 4)                   // 8 MB fp32 embT[256][8192]
#define WS_GMIN  (WS_EMBT + (size_t)DIM * NCODES * 4)  // 64 MB fp32 [NPTS][512]
#define WS_AHL   (WS_GMIN + (size_t)NPTS * 512 * 4)    // 48 MB
#define WS_BHL   (WS_AHL + (size_t)NPTS * 768 * 2)     // 12 MB

typedef __attribute__((ext_vector_type(8))) short short8;
typedef __attribute__((ext_vector_type(4))) float f32x4;

__device__ inline void gl_lds16(const void* g, void* l) {
    __builtin_amdgcn_global_load_lds(
        (const __attribute__((address_space(1))) void*)g,
        (__attribute__((address_space(3))) void*)l, 16, 0, 0);
}

__device__ inline unsigned short f2bf(float f) {  // RNE float->bf16
    unsigned u = __float_as_uint(f);
    return (unsigned short)((u + 0x7FFFu + ((u >> 16) & 1u)) >> 16);
}
__device__ inline unsigned f2ord(float f) {       // monotone float->uint
    unsigned u = __float_as_uint(f);
    return (u & 0x80000000u) ? ~u : (u | 0x80000000u);
}

// ---------------------------------------------------------------------------
__global__ __launch_bounds__(256) void k_prep(const float* __restrict__ ee,
                                              float* __restrict__ out5,
                                              int* __restrict__ cnt,
                                              double* __restrict__ loss) {
    int i = blockIdx.x * blockDim.x + threadIdx.x;
    int stride = gridDim.x * blockDim.x;
    for (int j = i; j < NCODES * DIM; j += stride)
        out5[j] = DECAYF * ee[j];
    if (i < NCODES) cnt[i] = 0;
    if (i == 0) *loss = 0.0;
}

// ---------------------------------------------------------------------------
__global__ __launch_bounds__(256) void k_rownorm(const float* __restrict__ x,
                                                 float* __restrict__ outn,
                                                 int nrows) {
    int w = (blockIdx.x * blockDim.x + threadIdx.x) >> 6;
    int lane = threadIdx.x & 63;
    if (w >= nrows) return;
    const float4 v = *(const float4*)(x + (size_t)w * DIM + 4 * lane);
    float q0 = v.x * v.x, q1 = v.y * v.y, q2 = v.z * v.z, q3 = v.w * v.w;
    double s = (double)q0 + (double)q1 + (double)q2 + (double)q3;
    #pragma unroll
    for (int off = 32; off > 0; off >>= 1) s += __shfl_down(s, off);
    if (lane == 0) outn[w] = (float)s;
}

// ---------------------------------------------------------------------------
// hi/lo bf16 split. mode 0 (z): cols [hi | lo | hi]; mode 1 (e): [hi | hi | lo]
__global__ __launch_bounds__(256) void k_split(const float* __restrict__ x,
                                               unsigned short* __restrict__ dst,
                                               int nelem, int mode) {
    int i = blockIdx.x * blockDim.x + threadIdx.x;
    int stride = gridDim.x * blockDim.x;
    for (int j = i; j < nelem; j += stride) {
        float v = x[j];
        unsigned short h = f2bf(v);
        float hf = __uint_as_float((unsigned)h << 16);
        unsigned short lo = f2bf(v - hf);
        int row = j >> 8, d = j & 255;
        size_t b = (size_t)row * 768 + d;
        if (mode == 0) { dst[b] = h;  dst[b + 256] = lo; dst[b + 512] = h; }
        else           { dst[b] = h;  dst[b + 256] = h;  dst[b + 512] = lo; }
    }
}

// ---------------------------------------------------------------------------
// transpose emb [8192][256] -> embT [256][8192] (fp32, bit-preserving)
__global__ __launch_bounds__(256) void k_transpose(const float* __restrict__ emb,
                                                   float* __restrict__ embT) {
    __shared__ float tile[32][33];
    int c0 = blockIdx.x * 32, d0 = blockIdx.y * 32;
    int tx = threadIdx.x & 31, ty = threadIdx.x >> 5;  // 8 rows
    #pragma unroll
    for (int r = 0; r < 4; ++r)
        tile[ty + r * 8][tx] = emb[(size_t)(c0 + ty + r * 8) * DIM + d0 + tx];
    __syncthreads();
    #pragma unroll
    for (int r = 0; r < 4; ++r)
        embT[(size_t)(d0 + ty + r * 8) * NCODES + c0 + tx] = tile[tx][ty + r * 8];
}

// ---------------------------------------------------------------------------
// Phase 1: bf16 MFMA GEMM (M=32768, N=8192, K=768), fused epilogue writes a
// per-16-code-group approx min distance (float) to gmin[NPTS][512].
__global__ __launch_bounds__(256) void k_gemm_argmin(
    const unsigned short* __restrict__ Ahl,   // [NPTS][768] bf16 bits
    const unsigned short* __restrict__ Bhl,   // [NCODES][768] bf16 bits
    const float* __restrict__ en,
    float* __restrict__ gmin) {               // [NPTS][512]
    __shared__ __align__(16) unsigned short SBUF[16384];  // 32 KB: A | B

    const int t = threadIdx.x;
    const int w = t >> 6, l = t & 63;
    const int quad = l >> 4, l15 = l & 15;
    const int wr = w >> 1, wc = w & 1;
    const int mb = blockIdx.x >> 6, nb = blockIdx.x & 63;
    const int mBase = mb * 128, nBase = nb * 128;

    const int xr = (t & 7) ^ ((t >> 3) & 7);
    const int rrow = t >> 3;
    const unsigned short* ag[4];
    const unsigned short* bg[4];
    #pragma unroll
    for (int i = 0; i < 4; ++i) {
        ag[i] = Ahl + (size_t)(mBase + i * 32 + rrow) * 768 + xr * 8;
        bg[i] = Bhl + (size_t)(nBase + i * 32 + rrow) * 768 + xr * 8;
    }

    f32x4 acc[4][4];
    #pragma unroll
    for (int i = 0; i < 4; ++i)
        #pragma unroll
        for (int j = 0; j < 4; ++j)
            acc[i][j] = (f32x4){0.f, 0.f, 0.f, 0.f};

    for (int kt = 0; kt < 12; ++kt) {
        __syncthreads();
        #pragma unroll
        for (int i = 0; i < 4; ++i) {
            gl_lds16(ag[i], &SBUF[(i * 256 + w * 64) * 8]);
            gl_lds16(bg[i], &SBUF[8192 + (i * 256 + w * 64) * 8]);
            ag[i] += 64; bg[i] += 64;
        }
        __syncthreads();
        #pragma unroll
        for (int kk = 0; kk < 2; ++kk) {
            const int kc = kk * 4 + quad;
            short8 a[4], b[4];
            #pragma unroll
            for (int ti = 0; ti < 4; ++ti) {
                int m = wr * 64 + ti * 16 + l15;
                a[ti] = *(const short8*)&SBUF[(m * 8 + (kc ^ (m & 7))) * 8];
                int n = wc * 64 + ti * 16 + l15;
                b[ti] = *(const short8*)&SBUF[8192 + (n * 8 + (kc ^ (n & 7))) * 8];
            }
            #pragma unroll
            for (int ti = 0; ti < 4; ++ti)
                #pragma unroll
                for (int tj = 0; tj < 4; ++tj)
                    acc[ti][tj] = __builtin_amdgcn_mfma_f32_16x16x32_bf16(
                        a[ti], b[tj], acc[ti][tj], 0, 0, 0);
        }
    }

    // epilogue: per-lane min over tj (4 codes sharing col l15), stage in the
    // (now free) staging LDS as ov[wc][point][l15], then 16-code group minima.
    float enc[4];
    #pragma unroll
    for (int tj = 0; tj < 4; ++tj)
        enc[tj] = en[nBase + wc * 64 + tj * 16 + l15];

    __syncthreads();
    float* ov = (float*)SBUF;   // [2][128][16] = 16 KB
    #pragma unroll
    for (int ti = 0; ti < 4; ++ti) {
        #pragma unroll
        for (int r = 0; r < 4; ++r) {
            float dmin = enc[0] - 2.0f * acc[ti][0][r];
            #pragma unroll
            for (int tj = 1; tj < 4; ++tj)
                dmin = fminf(dmin, enc[tj] - 2.0f * acc[ti][tj][r]);
            int p = wr * 64 + ti * 16 + quad * 4 + r;
            ov[(wc * 128 + p) * 16 + l15] = dmin;
        }
    }
    __syncthreads();
    #pragma unroll
    for (int it = 0; it < 4; ++it) {
        int id = it * 256 + t;                 // (wcc*128 + p)*4 + sg
        int sg = id & 3;
        const float4 v = *(const float4*)&ov[(id >> 2) * 16 + sg * 4];
        float m = fminf(fminf(v.x, v.y), fminf(v.z, v.w));
        int pp = (id >> 2) & 127;
        int wcc = id >> 9;
        // group g = nb*8 + wcc*4 + sg contains codes
        //   nb*128 + wcc*64 + tj*16 + sg*4 + j   (tj,j in 0..3)
        gmin[(size_t)(mBase + pp) * 512 + nb * 8 + wcc * 4 + sg] = m;
    }
}

// ---------------------------------------------------------------------------
// Phase 2: one wave per point. Global approx min over 512 group minima;
// rescore flagged groups (16 codes via lanes 0-15, coalesced embT columns)
// with round-1 exact fp32 semantics.
__global__ __launch_bounds__(256) void k_phase2(
    const float* __restrict__ z, const float* __restrict__ embT,
    const float* __restrict__ A, const float* __restrict__ en,
    const float* __restrict__ gmin,
    int* __restrict__ widx, float* __restrict__ out1) {
    int wpt = (blockIdx.x << 2) + (threadIdx.x >> 6);  // point id
    int l = threadIdx.x & 63;

    const float* gp = gmin + (size_t)wpt * 512;
    float loc[8];
    #pragma unroll
    for (int i = 0; i < 8; ++i) loc[i] = gp[i * 64 + l];
    float m8 = loc[0];
    #pragma unroll
    for (int i = 1; i < 8; ++i) m8 = fminf(m8, loc[i]);
    #pragma unroll
    for (int off = 1; off < 64; off <<= 1) m8 = fminf(m8, __shfl_xor(m8, off));
    const float thresh = m8 + MARGIN;

    const float* zr = z + (size_t)wpt * DIM;
    const float Azn = A[wpt];
    unsigned long long best = ~0ull;
    #pragma unroll 1
    for (int i = 0; i < 8; ++i) {
        unsigned long long mask = __ballot(loc[i] <= thresh);
        while (mask) {
            int s = __ffsll((long long)mask) - 1;
            mask &= mask - 1;
            int gid = i * 64 + s;
            int cbase = (gid >> 3) * 128 + ((gid >> 2) & 1) * 64 + (gid & 3) * 4;
            int k = l & 15;
            int c = cbase + (k >> 2) * 16 + (k & 3);
            const float* ec = embT + c;
            float acc = 0.f;
            for (int d = 0; d < DIM; ++d)
                acc = fmaf(zr[d], ec[(size_t)d * NCODES], acc);
            float dist = (Azn - 2.0f * acc) + en[c];
            if (l < 16) {
                unsigned long long pk =
                    ((unsigned long long)f2ord(dist) << 32) | (unsigned)c;
                best = pk < best ? pk : best;
            }
        }
    }
    #pragma unroll
    for (int off = 1; off < 64; off <<= 1) {
        unsigned long long o = __shfl_xor(best, off);
        best = o < best ? o : best;
    }
    if (l == 0) {
        int idx = (int)(unsigned)best;
        widx[wpt] = idx;
        out1[wpt] = (float)idx;
    }
}

// ---------------------------------------------------------------------------
__global__ __launch_bounds__(256) void k_scatter(const float* __restrict__ z,
                                                 const float* __restrict__ emb,
                                                 const int* __restrict__ widx,
                                                 float* __restrict__ out0,
                                                 float* __restrict__ out5,
                                                 int* __restrict__ cnt,
                                                 double* __restrict__ loss) {
    int w = (blockIdx.x * blockDim.x + threadIdx.x) >> 6;  // point id
    int lane = threadIdx.x & 63;
    int idx = widx[w];
    const float4 zv = *(const float4*)(z + (size_t)w * DIM + 4 * lane);
    const float4 ev = *(const float4*)(emb + (size_t)idx * DIM + 4 * lane);

    float4 o;
    o.x = ev.x + (zv.x - ev.x);
    o.y = ev.y + (zv.y - ev.y);
    o.z = ev.z + (zv.z - ev.z);
    o.w = ev.w + (zv.w - ev.w);
    *(float4*)(out0 + (size_t)w * DIM + 4 * lane) = o;

    float* dst = out5 + (size_t)idx * DIM + 4 * lane;
    atomicAdd(dst + 0, ONE_MINUS_DECAYF * zv.x);
    atomicAdd(dst + 1, ONE_MINUS_DECAYF * zv.y);
    atomicAdd(dst + 2, ONE_MINUS_DECAYF * zv.z);
    atomicAdd(dst + 3, ONE_MINUS_DECAYF * zv.w);

    float t0 = ev.x - zv.x, t1 = ev.y - zv.y, t2 = ev.z - zv.z, t3 = ev.w - zv.w;
    float s0 = t0 * t0, s1 = t1 * t1, s2 = t2 * t2, s3 = t3 * t3;
    double ls = (double)s0 + (double)s1 + (double)s2 + (double)s3;
    #pragma unroll
    for (int off = 32; off > 0; off >>= 1) ls += __shfl_down(ls, off);
    if (lane == 0) {
        atomicAdd(loss, ls);
        atomicAdd(cnt + idx, 1);
    }
}

// ---------------------------------------------------------------------------
__global__ __launch_bounds__(256) void k_n(const float* __restrict__ ecs,
                                           const int* __restrict__ cnt,
                                           float* __restrict__ out4,
                                           float* __restrict__ s_out,
                                           const double* __restrict__ loss,
                                           float* __restrict__ out2) {
    __shared__ double red[256];
    __shared__ float nsh;
    int t = threadIdx.x;
    double local = 0.0;
    for (int k = t; k < NCODES; k += 256) {
        float ncs = ecs[k] * DECAYF + (float)cnt[k] * ONE_MINUS_DECAYF;
        out4[k] = ncs;
        local += (double)ncs;
    }
    red[t] = local;
    __syncthreads();
    for (int off = 128; off > 0; off >>= 1) {
        if (t < off) red[t] += red[t + off];
        __syncthreads();
    }
    if (t == 0) {
        nsh = (float)red[0];
        out2[0] = 0.25f * (float)(*loss / (double)((size_t)NPTS * DIM));
    }
    __syncthreads();
    float n = nsh;
    for (int k = t; k < NCODES; k += 256)
        s_out[k] = (out4[k] + EPSF) / (n + KEPSF) * n;
}

// ---------------------------------------------------------------------------
__global__ __launch_bounds__(256) void k_final(const float* __restrict__ out5,
                                               const float* __restrict__ s,
                                               float* __restrict__ out3) {
    int i = blockIdx.x * blockDim.x + threadIdx.x;
    int stride = gridDim.x * blockDim.x;
    for (int j = i; j < NCODES * DIM; j += stride)
        out3[j] = out5[j] / s[j >> 8];
}

// ---------------------------------------------------------------------------
extern "C" void kernel_launch(void* const* d_in, const int* in_sizes, int n_in,
                              void* d_out, int out_size, void* d_ws, size_t ws_size,
                              hipStream_t stream) {
    const float* z   = (const float*)d_in[0];
    const float* emb = (const float*)d_in[1];
    const float* ecs = (const float*)d_in[2];
    const float* eem = (const float*)d_in[3];

    float* out = (float*)d_out;
    float* out0 = out;                   // z_q_st         [8388608]
    float* out1 = out + 8388608;         // indices        [32768]
    float* out2 = out + 8421376;         // vq_loss        [1]
    float* out3 = out + 8421377;         // new_embedding  [2097152]
    float* out4 = out + 10518529;        // new_ema_cs     [8192]
    float* out5 = out + 10526721;        // new_ema_emb    [2097152]

    char* ws = (char*)d_ws;
    double* wloss = (double*)(ws + WS_LOSS);
    float*  wA    = (float*)(ws + WS_A);
    float*  wEn   = (float*)(ws + WS_EN);
    int*    wCnt  = (int*)(ws + WS_CNT);
    float*  wS    = (float*)(ws + WS_S);
    int*    wIdx  = (int*)(ws + WS_IDX);
    float*  wEmbT = (float*)(ws + WS_EMBT);
    float*  wGmin = (float*)(ws + WS_GMIN);
    unsigned short* wAhl = (unsigned short*)(ws + WS_AHL);
    unsigned short* wBhl = (unsigned short*)(ws + WS_BHL);

    hipLaunchKernelGGL(k_prep, dim3(2048), dim3(256), 0, stream, eem, out5, wCnt, wloss);
    hipLaunchKernelGGL(k_rownorm, dim3(NPTS / 4), dim3(256), 0, stream, z, wA, NPTS);
    hipLaunchKernelGGL(k_rownorm, dim3(NCODES / 4), dim3(256), 0, stream, emb, wEn, NCODES);
    hipLaunchKernelGGL(k_split, dim3(4096), dim3(256), 0, stream, z, wAhl, NPTS * DIM, 0);
    hipLaunchKernelGGL(k_split, dim3(2048), dim3(256), 0, stream, emb, wBhl, NCODES * DIM, 1);
    hipLaunchKernelGGL(k_transpose, dim3(256, 8), dim3(256), 0, stream, emb, wEmbT);
    hipLaunchKernelGGL(k_gemm_argmin, dim3((NPTS / 128) * (NCODES / 128)), dim3(256), 0, stream,
                       wAhl, wBhl, wEn, wGmin);
    hipLaunchKernelGGL(k_phase2, dim3(NPTS / 4), dim3(256), 0, stream,
                       z, wEmbT, wA, wEn, wGmin, wIdx, out1);
    hipLaunchKernelGGL(k_scatter, dim3(NPTS / 4), dim3(256), 0, stream,
                       z, emb, wIdx, out0, out5, wCnt, wloss);
    hipLaunchKernelGGL(k_n, dim3(1), dim3(256), 0, stream, ecs, wCnt, out4, wS, wloss, out2);
    hipLaunchKernelGGL(k_final, dim3(2048), dim3(256), 0, stream, out5, wS, out3);
}

// Round 4
// 906.665 us; speedup vs baseline: 2.9666x; 1.3168x over previous
//
#include <hip/hip_runtime.h>

#define NPTS   32768
#define NCODES 8192
#define DIM    256

#define DECAYF 0.99f
#define ONE_MINUS_DECAYF ((float)(1.0 - 0.99))
#define EPSF   1e-5f
#define KEPSF  ((float)(8192.0 * 1e-5))
#define MARGIN 0.05f

// workspace byte offsets
#define WS_LOSS  0
#define WS_A     1024                                  // fp32 [NPTS]
#define WS_EN    (WS_A + NPTS * 4)                     // fp32 [NCODES]
#define WS_CNT   (WS_EN + NCODES * 4)                  // int  [NCODES]
#define WS_S     (WS_CNT + NCODES * 4)                 // fp32 [NCODES] smoothed
#define WS_IDX   (WS_S + NCODES * 4)                   // int  [NPTS]
#define WS_OFFS  (WS_IDX + NPTS * 4)                   // int  [NCODES]
#define WS_CUR   (WS_OFFS + NCODES * 4)                // int  [NCODES]
#define WS_PLIST (WS_CUR + NCODES * 4)                 // int  [NPTS]
#define WS_EMBT  (WS_PLIST + NPTS * 4)                 // fp32 embT[256][8192]  8 MB
#define WS_GMIN  (WS_EMBT + (size_t)DIM * NCODES * 4)  // fp32 [NPTS][512]     64 MB
#define WS_AH    (WS_GMIN + (size_t)NPTS * 512 * 4)    // bf16 [NPTS][256]     16 MB
#define WS_BH    (WS_AH + (size_t)NPTS * DIM * 2)      // bf16 [NCODES][256]    4 MB

typedef __attribute__((ext_vector_type(8))) short short8;
typedef __attribute__((ext_vector_type(4))) float f32x4;

__device__ inline void gl_lds16(const void* g, void* l) {
    __builtin_amdgcn_global_load_lds(
        (const __attribute__((address_space(1))) void*)g,
        (__attribute__((address_space(3))) void*)l, 16, 0, 0);
}

__device__ inline unsigned short f2bf(float f) {  // RNE float->bf16
    unsigned u = __float_as_uint(f);
    return (unsigned short)((u + 0x7FFFu + ((u >> 16) & 1u)) >> 16);
}
__device__ inline unsigned f2ord(float f) {       // monotone float->uint
    unsigned u = __float_as_uint(f);
    return (u & 0x80000000u) ? ~u : (u | 0x80000000u);
}

// ---------------------------------------------------------------------------
__global__ __launch_bounds__(256) void k_prep0(int* __restrict__ cnt,
                                               double* __restrict__ loss) {
    int i = blockIdx.x * blockDim.x + threadIdx.x;
    if (i < NCODES) cnt[i] = 0;
    if (i == 0) *loss = 0.0;
}

// ---------------------------------------------------------------------------
__global__ __launch_bounds__(256) void k_rownorm(const float* __restrict__ x,
                                                 float* __restrict__ outn,
                                                 int nrows) {
    int w = (blockIdx.x * blockDim.x + threadIdx.x) >> 6;
    int lane = threadIdx.x & 63;
    if (w >= nrows) return;
    const float4 v = *(const float4*)(x + (size_t)w * DIM + 4 * lane);
    float q0 = v.x * v.x, q1 = v.y * v.y, q2 = v.z * v.z, q3 = v.w * v.w;
    double s = (double)q0 + (double)q1 + (double)q2 + (double)q3;
    #pragma unroll
    for (int off = 32; off > 0; off >>= 1) s += __shfl_down(s, off);
    if (lane == 0) outn[w] = (float)s;
}

// ---------------------------------------------------------------------------
// elementwise fp32 -> bf16-hi
__global__ __launch_bounds__(256) void k_split(const float* __restrict__ x,
                                               unsigned short* __restrict__ dst,
                                               int nelem) {
    int i = blockIdx.x * blockDim.x + threadIdx.x;
    int stride = gridDim.x * blockDim.x;
    for (int j = i; j < nelem; j += stride)
        dst[j] = f2bf(x[j]);
}

// ---------------------------------------------------------------------------
// transpose emb [8192][256] -> embT [256][8192] (fp32, bit-preserving)
__global__ __launch_bounds__(256) void k_transpose(const float* __restrict__ emb,
                                                   float* __restrict__ embT) {
    __shared__ float tile[32][33];
    int c0 = blockIdx.x * 32, d0 = blockIdx.y * 32;
    int tx = threadIdx.x & 31, ty = threadIdx.x >> 5;  // 8 rows
    #pragma unroll
    for (int r = 0; r < 4; ++r)
        tile[ty + r * 8][tx] = emb[(size_t)(c0 + ty + r * 8) * DIM + d0 + tx];
    __syncthreads();
    #pragma unroll
    for (int r = 0; r < 4; ++r)
        embT[(size_t)(d0 + ty + r * 8) * NCODES + c0 + tx] = tile[tx][ty + r * 8];
}

// ---------------------------------------------------------------------------
// Phase 1: bf16-hi MFMA GEMM (M=32768, N=8192, K=256), fused epilogue writes
// per-16-code-group approx min distance (float) to gmin[NPTS][512].
__global__ __launch_bounds__(256) void k_gemm_argmin(
    const unsigned short* __restrict__ Ah,    // [NPTS][256] bf16 bits
    const unsigned short* __restrict__ Bh,    // [NCODES][256] bf16 bits
    const float* __restrict__ en,
    float* __restrict__ gmin) {               // [NPTS][512]
    __shared__ __align__(16) unsigned short SBUF[16384];  // 32 KB: A | B

    const int t = threadIdx.x;
    const int w = t >> 6, l = t & 63;
    const int quad = l >> 4, l15 = l & 15;
    const int wr = w >> 1, wc = w & 1;
    const int mb = blockIdx.x >> 6, nb = blockIdx.x & 63;
    const int mBase = mb * 128, nBase = nb * 128;

    // staging swizzle: slot s covers (row=s>>3, x=s&7, kchunk = x ^ (row&7))
    const int xr = (t & 7) ^ ((t >> 3) & 7);
    const int rrow = t >> 3;
    const unsigned short* ag[4];
    const unsigned short* bg[4];
    #pragma unroll
    for (int i = 0; i < 4; ++i) {
        ag[i] = Ah + (size_t)(mBase + i * 32 + rrow) * DIM + xr * 8;
        bg[i] = Bh + (size_t)(nBase + i * 32 + rrow) * DIM + xr * 8;
    }

    f32x4 acc[4][4];
    #pragma unroll
    for (int i = 0; i < 4; ++i)
        #pragma unroll
        for (int j = 0; j < 4; ++j)
            acc[i][j] = (f32x4){0.f, 0.f, 0.f, 0.f};

    for (int kt = 0; kt < 4; ++kt) {
        __syncthreads();
        #pragma unroll
        for (int i = 0; i < 4; ++i) {
            gl_lds16(ag[i], &SBUF[(i * 256 + w * 64) * 8]);
            gl_lds16(bg[i], &SBUF[8192 + (i * 256 + w * 64) * 8]);
            ag[i] += 64; bg[i] += 64;
        }
        __syncthreads();
        #pragma unroll
        for (int kk = 0; kk < 2; ++kk) {
            const int kc = kk * 4 + quad;
            short8 a[4], b[4];
            #pragma unroll
            for (int ti = 0; ti < 4; ++ti) {
                int m = wr * 64 + ti * 16 + l15;
                a[ti] = *(const short8*)&SBUF[(m * 8 + (kc ^ (m & 7))) * 8];
                int n = wc * 64 + ti * 16 + l15;
                b[ti] = *(const short8*)&SBUF[8192 + (n * 8 + (kc ^ (n & 7))) * 8];
            }
            #pragma unroll
            for (int ti = 0; ti < 4; ++ti)
                #pragma unroll
                for (int tj = 0; tj < 4; ++tj)
                    acc[ti][tj] = __builtin_amdgcn_mfma_f32_16x16x32_bf16(
                        a[ti], b[tj], acc[ti][tj], 0, 0, 0);
        }
    }

    // epilogue: per-lane min over tj, stage in freed staging LDS, then
    // 16-code group minima to gmin.
    float enc[4];
    #pragma unroll
    for (int tj = 0; tj < 4; ++tj)
        enc[tj] = en[nBase + wc * 64 + tj * 16 + l15];

    __syncthreads();
    float* ov = (float*)SBUF;   // [2][128][16] = 16 KB
    #pragma unroll
    for (int ti = 0; ti < 4; ++ti) {
        #pragma unroll
        for (int r = 0; r < 4; ++r) {
            float dmin = enc[0] - 2.0f * acc[ti][0][r];
            #pragma unroll
            for (int tj = 1; tj < 4; ++tj)
                dmin = fminf(dmin, enc[tj] - 2.0f * acc[ti][tj][r]);
            int p = wr * 64 + ti * 16 + quad * 4 + r;
            ov[(wc * 128 + p) * 16 + l15] = dmin;
        }
    }
    __syncthreads();
    #pragma unroll
    for (int it = 0; it < 4; ++it) {
        int id = it * 256 + t;                 // (wcc*128 + p)*4 + sg
        int sg = id & 3;
        const float4 v = *(const float4*)&ov[(id >> 2) * 16 + sg * 4];
        float m = fminf(fminf(v.x, v.y), fminf(v.z, v.w));
        int pp = (id >> 2) & 127;
        int wcc = id >> 9;
        gmin[(size_t)(mBase + pp) * 512 + nb * 8 + wcc * 4 + sg] = m;
    }
}

// ---------------------------------------------------------------------------
// Phase 2: one wave per point. Approx global min over 512 group minima;
// rescore flagged groups exactly (round-1 fp32 semantics, coalesced embT).
// Also builds the int histogram for the counting sort.
__global__ __launch_bounds__(256) void k_phase2(
    const float* __restrict__ z, const float* __restrict__ embT,
    const float* __restrict__ A, const float* __restrict__ en,
    const float* __restrict__ gmin,
    int* __restrict__ widx, float* __restrict__ out1,
    int* __restrict__ cnt) {
    int wpt = (blockIdx.x << 2) + (threadIdx.x >> 6);  // point id
    int l = threadIdx.x & 63;

    const float* gp = gmin + (size_t)wpt * 512;
    float loc[8];
    #pragma unroll
    for (int i = 0; i < 8; ++i) loc[i] = gp[i * 64 + l];
    float m8 = loc[0];
    #pragma unroll
    for (int i = 1; i < 8; ++i) m8 = fminf(m8, loc[i]);
    #pragma unroll
    for (int off = 1; off < 64; off <<= 1) m8 = fminf(m8, __shfl_xor(m8, off));
    const float thresh = m8 + MARGIN;

    const float* zr = z + (size_t)wpt * DIM;
    const float Azn = A[wpt];
    unsigned long long best = ~0ull;
    #pragma unroll 1
    for (int i = 0; i < 8; ++i) {
        unsigned long long mask = __ballot(loc[i] <= thresh);
        while (mask) {
            int s = __ffsll((long long)mask) - 1;
            mask &= mask - 1;
            int gid = i * 64 + s;
            int cbase = (gid >> 3) * 128 + ((gid >> 2) & 1) * 64 + (gid & 3) * 4;
            int k = l & 15;
            int c = cbase + (k >> 2) * 16 + (k & 3);
            const float* ec = embT + c;
            float acc = 0.f;
            for (int d = 0; d < DIM; ++d)
                acc = fmaf(zr[d], ec[(size_t)d * NCODES], acc);
            float dist = (Azn - 2.0f * acc) + en[c];
            if (l < 16) {
                unsigned long long pk =
                    ((unsigned long long)f2ord(dist) << 32) | (unsigned)c;
                best = pk < best ? pk : best;
            }
        }
    }
    #pragma unroll
    for (int off = 1; off < 64; off <<= 1) {
        unsigned long long o = __shfl_xor(best, off);
        best = o < best ? o : best;
    }
    if (l == 0) {
        int idx = (int)(unsigned)best;
        widx[wpt] = idx;
        out1[wpt] = (float)idx;
        atomicAdd(cnt + idx, 1);
    }
}

// ---------------------------------------------------------------------------
// single block: exclusive prefix of cnt -> offs (+cursor copy);
// out4 = ecs*0.99 + cnt*0.01; n = sum(out4); smoothed -> s_out.
__global__ __launch_bounds__(256) void k_scan(const int* __restrict__ cnt,
                                              const float* __restrict__ ecs,
                                              int* __restrict__ offs,
                                              int* __restrict__ cursor,
                                              float* __restrict__ out4,
                                              float* __restrict__ s_out) {
    __shared__ int ps[256];
    __shared__ double rd[256];
    __shared__ float nsh;
    int t = threadIdx.x;
    int base = t * 32;
    int loc[32];
    int s = 0;
    double nl = 0.0;
    #pragma unroll
    for (int i = 0; i < 32; ++i) {
        int c = cnt[base + i];
        loc[i] = c;
        s += c;
        float f = ecs[base + i] * DECAYF + (float)c * ONE_MINUS_DECAYF;
        out4[base + i] = f;
        nl += (double)f;
    }
    ps[t] = s;
    rd[t] = nl;
    __syncthreads();
    for (int off = 1; off < 256; off <<= 1) {
        int v = (t >= off) ? ps[t - off] : 0;
        __syncthreads();
        ps[t] += v;
        __syncthreads();
    }
    for (int off = 128; off > 0; off >>= 1) {
        if (t < off) rd[t] += rd[t + off];
        __syncthreads();
    }
    if (t == 0) nsh = (float)rd[0];
    __syncthreads();
    int run = (t == 0) ? 0 : ps[t - 1];
    #pragma unroll
    for (int i = 0; i < 32; ++i) {
        offs[base + i] = run;
        cursor[base + i] = run;
        run += loc[i];
    }
    float n = nsh;
    for (int k = t; k < NCODES; k += 256)
        s_out[k] = (out4[k] + EPSF) / (n + KEPSF) * n;
}

// ---------------------------------------------------------------------------
__global__ __launch_bounds__(256) void k_place(const int* __restrict__ widx,
                                               int* __restrict__ cursor,
                                               int* __restrict__ plist) {
    int p = blockIdx.x * 256 + threadIdx.x;
    int idx = widx[p];
    int slot = atomicAdd(&cursor[idx], 1);
    plist[slot] = p;
}

// ---------------------------------------------------------------------------
// z_q_st + commitment loss (no fp32 scatter atomics)
__global__ __launch_bounds__(256) void k_zq(const float* __restrict__ z,
                                            const float* __restrict__ emb,
                                            const int* __restrict__ widx,
                                            float* __restrict__ out0,
                                            double* __restrict__ loss) {
    int w = (blockIdx.x * blockDim.x + threadIdx.x) >> 6;  // point id
    int lane = threadIdx.x & 63;
    int idx = widx[w];
    const float4 zv = *(const float4*)(z + (size_t)w * DIM + 4 * lane);
    const float4 ev = *(const float4*)(emb + (size_t)idx * DIM + 4 * lane);

    float4 o;
    o.x = ev.x + (zv.x - ev.x);
    o.y = ev.y + (zv.y - ev.y);
    o.z = ev.z + (zv.z - ev.z);
    o.w = ev.w + (zv.w - ev.w);
    *(float4*)(out0 + (size_t)w * DIM + 4 * lane) = o;

    float t0 = ev.x - zv.x, t1 = ev.y - zv.y, t2 = ev.z - zv.z, t3 = ev.w - zv.w;
    float s0 = t0 * t0, s1 = t1 * t1, s2 = t2 * t2, s3 = t3 * t3;
    double ls = (double)s0 + (double)s1 + (double)s2 + (double)s3;
    #pragma unroll
    for (int off = 32; off > 0; off >>= 1) ls += __shfl_down(ls, off);
    if (lane == 0) atomicAdd(loss, ls);
}

// ---------------------------------------------------------------------------
// one wave per code: out5 = 0.99*eem + 0.01*sum(z[points of code])
__global__ __launch_bounds__(256) void k_dw(const float* __restrict__ z,
                                            const float* __restrict__ eem,
                                            const int* __restrict__ offs,
                                            const int* __restrict__ cnt,
                                            const int* __restrict__ plist,
                                            float* __restrict__ out5) {
    int c = blockIdx.x * 4 + (threadIdx.x >> 6);
    int lane = threadIdx.x & 63;
    int beg = offs[c], num = cnt[c];
    float4 acc = make_float4(0.f, 0.f, 0.f, 0.f);
    for (int j = 0; j < num; ++j) {
        int p = plist[beg + j];
        const float4 v = *(const float4*)(z + (size_t)p * DIM + 4 * lane);
        acc.x += v.x; acc.y += v.y; acc.z += v.z; acc.w += v.w;
    }
    const float4 e = *(const float4*)(eem + (size_t)c * DIM + 4 * lane);
    float4 o;
    o.x = e.x * DECAYF + acc.x * ONE_MINUS_DECAYF;
    o.y = e.y * DECAYF + acc.y * ONE_MINUS_DECAYF;
    o.z = e.z * DECAYF + acc.z * ONE_MINUS_DECAYF;
    o.w = e.w * DECAYF + acc.w * ONE_MINUS_DECAYF;
    *(float4*)(out5 + (size_t)c * DIM + 4 * lane) = o;
}

// ---------------------------------------------------------------------------
__global__ __launch_bounds__(256) void k_final(const float* __restrict__ out5,
                                               const float* __restrict__ s,
                                               float* __restrict__ out3,
                                               const double* __restrict__ loss,
                                               float* __restrict__ out2) {
    int i = blockIdx.x * blockDim.x + threadIdx.x;
    int stride = gridDim.x * blockDim.x;
    for (int j = i; j < NCODES * DIM; j += stride)
        out3[j] = out5[j] / s[j >> 8];
    if (i == 0)
        out2[0] = 0.25f * (float)(*loss / (double)((size_t)NPTS * DIM));
}

// ---------------------------------------------------------------------------
extern "C" void kernel_launch(void* const* d_in, const int* in_sizes, int n_in,
                              void* d_out, int out_size, void* d_ws, size_t ws_size,
                              hipStream_t stream) {
    const float* z   = (const float*)d_in[0];
    const float* emb = (const float*)d_in[1];
    const float* ecs = (const float*)d_in[2];
    const float* eem = (const float*)d_in[3];

    float* out = (float*)d_out;
    float* out0 = out;                   // z_q_st         [8388608]
    float* out1 = out + 8388608;         // indices        [32768]
    float* out2 = out + 8421376;         // vq_loss        [1]
    float* out3 = out + 8421377;         // new_embedding  [2097152]
    float* out4 = out + 10518529;        // new_ema_cs     [8192]
    float* out5 = out + 10526721;        // new_ema_emb    [2097152]

    char* ws = (char*)d_ws;
    double* wloss = (double*)(ws + WS_LOSS);
    float*  wA    = (float*)(ws + WS_A);
    float*  wEn   = (float*)(ws + WS_EN);
    int*    wCnt  = (int*)(ws + WS_CNT);
    float*  wS    = (float*)(ws + WS_S);
    int*    wIdx  = (int*)(ws + WS_IDX);
    int*    wOffs = (int*)(ws + WS_OFFS);
    int*    wCur  = (int*)(ws + WS_CUR);
    int*    wPl   = (int*)(ws + WS_PLIST);
    float*  wEmbT = (float*)(ws + WS_EMBT);
    float*  wGmin = (float*)(ws + WS_GMIN);
    unsigned short* wAh = (unsigned short*)(ws + WS_AH);
    unsigned short* wBh = (unsigned short*)(ws + WS_BH);

    hipLaunchKernelGGL(k_prep0, dim3(32), dim3(256), 0, stream, wCnt, wloss);
    hipLaunchKernelGGL(k_rownorm, dim3(NPTS / 4), dim3(256), 0, stream, z, wA, NPTS);
    hipLaunchKernelGGL(k_rownorm, dim3(NCODES / 4), dim3(256), 0, stream, emb, wEn, NCODES);
    hipLaunchKernelGGL(k_split, dim3(4096), dim3(256), 0, stream, z, wAh, NPTS * DIM);
    hipLaunchKernelGGL(k_split, dim3(1024), dim3(256), 0, stream, emb, wBh, NCODES * DIM);
    hipLaunchKernelGGL(k_transpose, dim3(256, 8), dim3(256), 0, stream, emb, wEmbT);
    hipLaunchKernelGGL(k_gemm_argmin, dim3((NPTS / 128) * (NCODES / 128)), dim3(256), 0, stream,
                       wAh, wBh, wEn, wGmin);
    hipLaunchKernelGGL(k_phase2, dim3(NPTS / 4), dim3(256), 0, stream,
                       z, wEmbT, wA, wEn, wGmin, wIdx, out1, wCnt);
    hipLaunchKernelGGL(k_scan, dim3(1), dim3(256), 0, stream,
                       wCnt, ecs, wOffs, wCur, out4, wS);
    hipLaunchKernelGGL(k_place, dim3(NPTS / 256), dim3(256), 0, stream, wIdx, wCur, wPl);
    hipLaunchKernelGGL(k_zq, dim3(NPTS / 4), dim3(256), 0, stream, z, emb, wIdx, out0, wloss);
    hipLaunchKernelGGL(k_dw, dim3(NCODES / 4), dim3(256), 0, stream,
                       z, eem, wOffs, wCnt, wPl, out5);
    hipLaunchKernelGGL(k_final, dim3(2048), dim3(256), 0, stream, out5, wS, out3, wloss, out2);
}

// Round 5
// 534.190 us; speedup vs baseline: 5.0351x; 1.6973x over previous
//
#include <hip/hip_runtime.h>

#define NPTS   32768
#define NCODES 8192
#define DIM    256

#define DECAYF 0.99f
#define ONE_MINUS_DECAYF ((float)(1.0 - 0.99))
#define EPSF   1e-5f
#define KEPSF  ((float)(8192.0 * 1e-5))
#define MARGIN 0.05f

// workspace byte offsets
#define WS_PART  0                                     // fp64 [8192] loss partials
#define WS_A     (WS_PART + NPTS / 4 * 8)              // fp32 [NPTS]
#define WS_EN    (WS_A + NPTS * 4)                     // fp32 [NCODES]
#define WS_CNT   (WS_EN + NCODES * 4)                  // int  [NCODES]
#define WS_S     (WS_CNT + NCODES * 4)                 // fp32 [NCODES] smoothed
#define WS_IDX   (WS_S + NCODES * 4)                   // int  [NPTS]
#define WS_OFFS  (WS_IDX + NPTS * 4)                   // int  [NCODES]
#define WS_CUR   (WS_OFFS + NCODES * 4)                // int  [NCODES]
#define WS_PLIST (WS_CUR + NCODES * 4)                 // int  [NPTS]
#define WS_EMBT  (WS_PLIST + NPTS * 4)                 // fp32 embT[256][8192]  8 MB
#define WS_GMIN  (WS_EMBT + (size_t)DIM * NCODES * 4)  // fp32 [NPTS][512]     64 MB
#define WS_AH    (WS_GMIN + (size_t)NPTS * 512 * 4)    // bf16 [NPTS][256]     16 MB
#define WS_BH    (WS_AH + (size_t)NPTS * DIM * 2)      // bf16 [NCODES][256]    4 MB

typedef __attribute__((ext_vector_type(8))) short short8;
typedef __attribute__((ext_vector_type(4))) float f32x4;

__device__ inline void gl_lds16(const void* g, void* l) {
    __builtin_amdgcn_global_load_lds(
        (const __attribute__((address_space(1))) void*)g,
        (__attribute__((address_space(3))) void*)l, 16, 0, 0);
}

__device__ inline unsigned short f2bf(float f) {  // RNE float->bf16
    unsigned u = __float_as_uint(f);
    return (unsigned short)((u + 0x7FFFu + ((u >> 16) & 1u)) >> 16);
}
__device__ inline unsigned f2ord(float f) {       // monotone float->uint
    unsigned u = __float_as_uint(f);
    return (u & 0x80000000u) ? ~u : (u | 0x80000000u);
}

// ---------------------------------------------------------------------------
__global__ __launch_bounds__(256) void k_prep0(int* __restrict__ cnt) {
    int i = blockIdx.x * blockDim.x + threadIdx.x;
    if (i < NCODES) cnt[i] = 0;
}

// ---------------------------------------------------------------------------
__global__ __launch_bounds__(256) void k_rownorm(const float* __restrict__ x,
                                                 float* __restrict__ outn,
                                                 int nrows) {
    int w = (blockIdx.x * blockDim.x + threadIdx.x) >> 6;
    int lane = threadIdx.x & 63;
    if (w >= nrows) return;
    const float4 v = *(const float4*)(x + (size_t)w * DIM + 4 * lane);
    float q0 = v.x * v.x, q1 = v.y * v.y, q2 = v.z * v.z, q3 = v.w * v.w;
    double s = (double)q0 + (double)q1 + (double)q2 + (double)q3;
    #pragma unroll
    for (int off = 32; off > 0; off >>= 1) s += __shfl_down(s, off);
    if (lane == 0) outn[w] = (float)s;
}

// ---------------------------------------------------------------------------
// elementwise fp32 -> bf16-hi
__global__ __launch_bounds__(256) void k_split(const float* __restrict__ x,
                                               unsigned short* __restrict__ dst,
                                               int nelem) {
    int i = blockIdx.x * blockDim.x + threadIdx.x;
    int stride = gridDim.x * blockDim.x;
    for (int j = i; j < nelem; j += stride)
        dst[j] = f2bf(x[j]);
}

// ---------------------------------------------------------------------------
// transpose emb [8192][256] -> embT [256][8192] (fp32, bit-preserving)
__global__ __launch_bounds__(256) void k_transpose(const float* __restrict__ emb,
                                                   float* __restrict__ embT) {
    __shared__ float tile[32][33];
    int c0 = blockIdx.x * 32, d0 = blockIdx.y * 32;
    int tx = threadIdx.x & 31, ty = threadIdx.x >> 5;  // 8 rows
    #pragma unroll
    for (int r = 0; r < 4; ++r)
        tile[ty + r * 8][tx] = emb[(size_t)(c0 + ty + r * 8) * DIM + d0 + tx];
    __syncthreads();
    #pragma unroll
    for (int r = 0; r < 4; ++r)
        embT[(size_t)(d0 + ty + r * 8) * NCODES + c0 + tx] = tile[tx][ty + r * 8];
}

// ---------------------------------------------------------------------------
// Phase 1: bf16-hi MFMA GEMM (M=32768, N=8192, K=256), fused epilogue writes
// per-16-code-group approx min distance (float) to gmin[NPTS][512].
__global__ __launch_bounds__(256) void k_gemm_argmin(
    const unsigned short* __restrict__ Ah,    // [NPTS][256] bf16 bits
    const unsigned short* __restrict__ Bh,    // [NCODES][256] bf16 bits
    const float* __restrict__ en,
    float* __restrict__ gmin) {               // [NPTS][512]
    __shared__ __align__(16) unsigned short SBUF[16384];  // 32 KB: A | B

    const int t = threadIdx.x;
    const int w = t >> 6, l = t & 63;
    const int quad = l >> 4, l15 = l & 15;
    const int wr = w >> 1, wc = w & 1;
    const int mb = blockIdx.x >> 6, nb = blockIdx.x & 63;
    const int mBase = mb * 128, nBase = nb * 128;

    // staging swizzle: slot s covers (row=s>>3, x=s&7, kchunk = x ^ (row&7))
    const int xr = (t & 7) ^ ((t >> 3) & 7);
    const int rrow = t >> 3;
    const unsigned short* ag[4];
    const unsigned short* bg[4];
    #pragma unroll
    for (int i = 0; i < 4; ++i) {
        ag[i] = Ah + (size_t)(mBase + i * 32 + rrow) * DIM + xr * 8;
        bg[i] = Bh + (size_t)(nBase + i * 32 + rrow) * DIM + xr * 8;
    }

    f32x4 acc[4][4];
    #pragma unroll
    for (int i = 0; i < 4; ++i)
        #pragma unroll
        for (int j = 0; j < 4; ++j)
            acc[i][j] = (f32x4){0.f, 0.f, 0.f, 0.f};

    for (int kt = 0; kt < 4; ++kt) {
        __syncthreads();
        #pragma unroll
        for (int i = 0; i < 4; ++i) {
            gl_lds16(ag[i], &SBUF[(i * 256 + w * 64) * 8]);
            gl_lds16(bg[i], &SBUF[8192 + (i * 256 + w * 64) * 8]);
            ag[i] += 64; bg[i] += 64;
        }
        __syncthreads();
        #pragma unroll
        for (int kk = 0; kk < 2; ++kk) {
            const int kc = kk * 4 + quad;
            short8 a[4], b[4];
            #pragma unroll
            for (int ti = 0; ti < 4; ++ti) {
                int m = wr * 64 + ti * 16 + l15;
                a[ti] = *(const short8*)&SBUF[(m * 8 + (kc ^ (m & 7))) * 8];
                int n = wc * 64 + ti * 16 + l15;
                b[ti] = *(const short8*)&SBUF[8192 + (n * 8 + (kc ^ (n & 7))) * 8];
            }
            #pragma unroll
            for (int ti = 0; ti < 4; ++ti)
                #pragma unroll
                for (int tj = 0; tj < 4; ++tj)
                    acc[ti][tj] = __builtin_amdgcn_mfma_f32_16x16x32_bf16(
                        a[ti], b[tj], acc[ti][tj], 0, 0, 0);
        }
    }

    // epilogue: per-lane min over tj, stage in freed staging LDS, then
    // 16-code group minima to gmin.
    float enc[4];
    #pragma unroll
    for (int tj = 0; tj < 4; ++tj)
        enc[tj] = en[nBase + wc * 64 + tj * 16 + l15];

    __syncthreads();
    float* ov = (float*)SBUF;   // [2][128][16] = 16 KB
    #pragma unroll
    for (int ti = 0; ti < 4; ++ti) {
        #pragma unroll
        for (int r = 0; r < 4; ++r) {
            float dmin = enc[0] - 2.0f * acc[ti][0][r];
            #pragma unroll
            for (int tj = 1; tj < 4; ++tj)
                dmin = fminf(dmin, enc[tj] - 2.0f * acc[ti][tj][r]);
            int p = wr * 64 + ti * 16 + quad * 4 + r;
            ov[(wc * 128 + p) * 16 + l15] = dmin;
        }
    }
    __syncthreads();
    #pragma unroll
    for (int it = 0; it < 4; ++it) {
        int id = it * 256 + t;                 // (wcc*128 + p)*4 + sg
        int sg = id & 3;
        const float4 v = *(const float4*)&ov[(id >> 2) * 16 + sg * 4];
        float m = fminf(fminf(v.x, v.y), fminf(v.z, v.w));
        int pp = (id >> 2) & 127;
        int wcc = id >> 9;
        gmin[(size_t)(mBase + pp) * 512 + nb * 8 + wcc * 4 + sg] = m;
    }
}

// ---------------------------------------------------------------------------
// Phase 2: one wave per point. Approx global min over 512 group minima;
// rescore flagged groups exactly (round-1 fp32 semantics, coalesced embT).
// Also builds the int histogram for the counting sort.
__global__ __launch_bounds__(256) void k_phase2(
    const float* __restrict__ z, const float* __restrict__ embT,
    const float* __restrict__ A, const float* __restrict__ en,
    const float* __restrict__ gmin,
    int* __restrict__ widx, float* __restrict__ out1,
    int* __restrict__ cnt) {
    int wpt = (blockIdx.x << 2) + (threadIdx.x >> 6);  // point id
    int l = threadIdx.x & 63;

    const float* gp = gmin + (size_t)wpt * 512;
    float loc[8];
    #pragma unroll
    for (int i = 0; i < 8; ++i) loc[i] = gp[i * 64 + l];
    float m8 = loc[0];
    #pragma unroll
    for (int i = 1; i < 8; ++i) m8 = fminf(m8, loc[i]);
    #pragma unroll
    for (int off = 1; off < 64; off <<= 1) m8 = fminf(m8, __shfl_xor(m8, off));
    const float thresh = m8 + MARGIN;

    const float* zr = z + (size_t)wpt * DIM;
    const float Azn = A[wpt];
    unsigned long long best = ~0ull;
    #pragma unroll 1
    for (int i = 0; i < 8; ++i) {
        unsigned long long mask = __ballot(loc[i] <= thresh);
        while (mask) {
            int s = __ffsll((long long)mask) - 1;
            mask &= mask - 1;
            int gid = i * 64 + s;
            int cbase = (gid >> 3) * 128 + ((gid >> 2) & 1) * 64 + (gid & 3) * 4;
            int k = l & 15;
            int c = cbase + (k >> 2) * 16 + (k & 3);
            const float* ec = embT + c;
            float acc = 0.f;
            for (int d = 0; d < DIM; ++d)
                acc = fmaf(zr[d], ec[(size_t)d * NCODES], acc);
            float dist = (Azn - 2.0f * acc) + en[c];
            if (l < 16) {
                unsigned long long pk =
                    ((unsigned long long)f2ord(dist) << 32) | (unsigned)c;
                best = pk < best ? pk : best;
            }
        }
    }
    #pragma unroll
    for (int off = 1; off < 64; off <<= 1) {
        unsigned long long o = __shfl_xor(best, off);
        best = o < best ? o : best;
    }
    if (l == 0) {
        int idx = (int)(unsigned)best;
        widx[wpt] = idx;
        out1[wpt] = (float)idx;
        atomicAdd(cnt + idx, 1);
    }
}

// ---------------------------------------------------------------------------
// single block: exclusive prefix of cnt -> offs (+cursor copy);
// out4 = ecs*0.99 + cnt*0.01; n = sum(out4); smoothed -> s_out.
__global__ __launch_bounds__(256) void k_scan(const int* __restrict__ cnt,
                                              const float* __restrict__ ecs,
                                              int* __restrict__ offs,
                                              int* __restrict__ cursor,
                                              float* __restrict__ out4,
                                              float* __restrict__ s_out) {
    __shared__ int ps[256];
    __shared__ double rd[256];
    __shared__ float nsh;
    int t = threadIdx.x;
    int base = t * 32;
    int loc[32];
    int s = 0;
    double nl = 0.0;
    #pragma unroll
    for (int i = 0; i < 32; ++i) {
        int c = cnt[base + i];
        loc[i] = c;
        s += c;
        float f = ecs[base + i] * DECAYF + (float)c * ONE_MINUS_DECAYF;
        out4[base + i] = f;
        nl += (double)f;
    }
    ps[t] = s;
    rd[t] = nl;
    __syncthreads();
    for (int off = 1; off < 256; off <<= 1) {
        int v = (t >= off) ? ps[t - off] : 0;
        __syncthreads();
        ps[t] += v;
        __syncthreads();
    }
    for (int off = 128; off > 0; off >>= 1) {
        if (t < off) rd[t] += rd[t + off];
        __syncthreads();
    }
    if (t == 0) nsh = (float)rd[0];
    __syncthreads();
    int run = (t == 0) ? 0 : ps[t - 1];
    #pragma unroll
    for (int i = 0; i < 32; ++i) {
        offs[base + i] = run;
        cursor[base + i] = run;
        run += loc[i];
    }
    float n = nsh;
    for (int k = t; k < NCODES; k += 256)
        s_out[k] = (out4[k] + EPSF) / (n + KEPSF) * n;
}

// ---------------------------------------------------------------------------
__global__ __launch_bounds__(256) void k_place(const int* __restrict__ widx,
                                               int* __restrict__ cursor,
                                               int* __restrict__ plist) {
    int p = blockIdx.x * 256 + threadIdx.x;
    int idx = widx[p];
    int slot = atomicAdd(&cursor[idx], 1);
    plist[slot] = p;
}

// ---------------------------------------------------------------------------
// z_q_st + commitment-loss partials (no atomics; one double per block)
__global__ __launch_bounds__(256) void k_zq(const float* __restrict__ z,
                                            const float* __restrict__ emb,
                                            const int* __restrict__ widx,
                                            float* __restrict__ out0,
                                            double* __restrict__ part) {
    __shared__ double sred[4];
    int w = (blockIdx.x * blockDim.x + threadIdx.x) >> 6;  // point id
    int wv = threadIdx.x >> 6;
    int lane = threadIdx.x & 63;
    int idx = widx[w];
    const float4 zv = *(const float4*)(z + (size_t)w * DIM + 4 * lane);
    const float4 ev = *(const float4*)(emb + (size_t)idx * DIM + 4 * lane);

    float4 o;
    o.x = ev.x + (zv.x - ev.x);
    o.y = ev.y + (zv.y - ev.y);
    o.z = ev.z + (zv.z - ev.z);
    o.w = ev.w + (zv.w - ev.w);
    *(float4*)(out0 + (size_t)w * DIM + 4 * lane) = o;

    float t0 = ev.x - zv.x, t1 = ev.y - zv.y, t2 = ev.z - zv.z, t3 = ev.w - zv.w;
    float s0 = t0 * t0, s1 = t1 * t1, s2 = t2 * t2, s3 = t3 * t3;
    double ls = (double)s0 + (double)s1 + (double)s2 + (double)s3;
    #pragma unroll
    for (int off = 32; off > 0; off >>= 1) ls += __shfl_down(ls, off);
    if (lane == 0) sred[wv] = ls;
    __syncthreads();
    if (threadIdx.x == 0)
        part[blockIdx.x] = (sred[0] + sred[1]) + (sred[2] + sred[3]);
}

// ---------------------------------------------------------------------------
// single block: sum 8192 loss partials -> out2
__global__ __launch_bounds__(256) void k_loss(const double* __restrict__ part,
                                              float* __restrict__ out2) {
    __shared__ double red[256];
    int t = threadIdx.x;
    double s = 0.0;
    for (int i = t; i < NPTS / 4; i += 256) s += part[i];
    red[t] = s;
    __syncthreads();
    for (int off = 128; off > 0; off >>= 1) {
        if (t < off) red[t] += red[t + off];
        __syncthreads();
    }
    if (t == 0)
        out2[0] = 0.25f * (float)(red[0] / (double)((size_t)NPTS * DIM));
}

// ---------------------------------------------------------------------------
// one wave per code: out5 = 0.99*eem + 0.01*sum(z[points of code])
__global__ __launch_bounds__(256) void k_dw(const float* __restrict__ z,
                                            const float* __restrict__ eem,
                                            const int* __restrict__ offs,
                                            const int* __restrict__ cnt,
                                            const int* __restrict__ plist,
                                            float* __restrict__ out5) {
    int c = blockIdx.x * 4 + (threadIdx.x >> 6);
    int lane = threadIdx.x & 63;
    int beg = offs[c], num = cnt[c];
    float4 acc = make_float4(0.f, 0.f, 0.f, 0.f);
    for (int j = 0; j < num; ++j) {
        int p = plist[beg + j];
        const float4 v = *(const float4*)(z + (size_t)p * DIM + 4 * lane);
        acc.x += v.x; acc.y += v.y; acc.z += v.z; acc.w += v.w;
    }
    const float4 e = *(const float4*)(eem + (size_t)c * DIM + 4 * lane);
    float4 o;
    o.x = e.x * DECAYF + acc.x * ONE_MINUS_DECAYF;
    o.y = e.y * DECAYF + acc.y * ONE_MINUS_DECAYF;
    o.z = e.z * DECAYF + acc.z * ONE_MINUS_DECAYF;
    o.w = e.w * DECAYF + acc.w * ONE_MINUS_DECAYF;
    *(float4*)(out5 + (size_t)c * DIM + 4 * lane) = o;
}

// ---------------------------------------------------------------------------
__global__ __launch_bounds__(256) void k_final(const float* __restrict__ out5,
                                               const float* __restrict__ s,
                                               float* __restrict__ out3) {
    int i = blockIdx.x * blockDim.x + threadIdx.x;
    int stride = gridDim.x * blockDim.x;
    for (int j = i; j < NCODES * DIM; j += stride)
        out3[j] = out5[j] / s[j >> 8];
}

// ---------------------------------------------------------------------------
extern "C" void kernel_launch(void* const* d_in, const int* in_sizes, int n_in,
                              void* d_out, int out_size, void* d_ws, size_t ws_size,
                              hipStream_t stream) {
    const float* z   = (const float*)d_in[0];
    const float* emb = (const float*)d_in[1];
    const float* ecs = (const float*)d_in[2];
    const float* eem = (const float*)d_in[3];

    float* out = (float*)d_out;
    float* out0 = out;                   // z_q_st         [8388608]
    float* out1 = out + 8388608;         // indices        [32768]
    float* out2 = out + 8421376;         // vq_loss        [1]
    float* out3 = out + 8421377;         // new_embedding  [2097152]
    float* out4 = out + 10518529;        // new_ema_cs     [8192]
    float* out5 = out + 10526721;        // new_ema_emb    [2097152]

    char* ws = (char*)d_ws;
    double* wPart = (double*)(ws + WS_PART);
    float*  wA    = (float*)(ws + WS_A);
    float*  wEn   = (float*)(ws + WS_EN);
    int*    wCnt  = (int*)(ws + WS_CNT);
    float*  wS    = (float*)(ws + WS_S);
    int*    wIdx  = (int*)(ws + WS_IDX);
    int*    wOffs = (int*)(ws + WS_OFFS);
    int*    wCur  = (int*)(ws + WS_CUR);
    int*    wPl   = (int*)(ws + WS_PLIST);
    float*  wEmbT = (float*)(ws + WS_EMBT);
    float*  wGmin = (float*)(ws + WS_GMIN);
    unsigned short* wAh = (unsigned short*)(ws + WS_AH);
    unsigned short* wBh = (unsigned short*)(ws + WS_BH);

    hipLaunchKernelGGL(k_prep0, dim3(32), dim3(256), 0, stream, wCnt);
    hipLaunchKernelGGL(k_rownorm, dim3(NPTS / 4), dim3(256), 0, stream, z, wA, NPTS);
    hipLaunchKernelGGL(k_rownorm, dim3(NCODES / 4), dim3(256), 0, stream, emb, wEn, NCODES);
    hipLaunchKernelGGL(k_split, dim3(4096), dim3(256), 0, stream, z, wAh, NPTS * DIM);
    hipLaunchKernelGGL(k_split, dim3(1024), dim3(256), 0, stream, emb, wBh, NCODES * DIM);
    hipLaunchKernelGGL(k_transpose, dim3(256, 8), dim3(256), 0, stream, emb, wEmbT);
    hipLaunchKernelGGL(k_gemm_argmin, dim3((NPTS / 128) * (NCODES / 128)), dim3(256), 0, stream,
                       wAh, wBh, wEn, wGmin);
    hipLaunchKernelGGL(k_phase2, dim3(NPTS / 4), dim3(256), 0, stream,
                       z, wEmbT, wA, wEn, wGmin, wIdx, out1, wCnt);
    hipLaunchKernelGGL(k_scan, dim3(1), dim3(256), 0, stream,
                       wCnt, ecs, wOffs, wCur, out4, wS);
    hipLaunchKernelGGL(k_place, dim3(NPTS / 256), dim3(256), 0, stream, wIdx, wCur, wPl);
    hipLaunchKernelGGL(k_zq, dim3(NPTS / 4), dim3(256), 0, stream, z, emb, wIdx, out0, wPart);
    hipLaunchKernelGGL(k_loss, dim3(1), dim3(256), 0, stream, wPart, out2);
    hipLaunchKernelGGL(k_dw, dim3(NCODES / 4), dim3(256), 0, stream,
                       z, eem, wOffs, wCnt, wPl, out5);
    hipLaunchKernelGGL(k_final, dim3(2048), dim3(256), 0, stream, out5, wS, out3);
}